// Round 10
// baseline (199.139 us; speedup 1.0000x reference)
//
#include <hip/hip_runtime.h>
#include <hip/hip_bf16.h>
#include <cstdint>
#include <cstddef>

#define L_SEQ 4096
#define BATCH_N 4
#define HID 1024
#define DH 256
// log2(0.96875)
#define LOG2_GAMMA (-0.045803689613124953f)
// 0.96875^-32
#define INV_GAMMA32 (2.7620582f)

typedef __attribute__((ext_vector_type(8))) short short8;
typedef __attribute__((ext_vector_type(4))) float floatx4;

__device__ __forceinline__ unsigned short f2bf(float f) {
    union { float f; unsigned int u; } v; v.f = f;
    unsigned int r = (v.u + 0x7FFFu + ((v.u >> 16) & 1u)) >> 16;  // RNE
    return (unsigned short)r;
}

__device__ __forceinline__ void async_copy16(const unsigned short* gsrc,
                                             unsigned short* lds) {
    __builtin_amdgcn_global_load_lds(
        (const __attribute__((address_space(1))) unsigned int*)gsrc,
        (__attribute__((address_space(3))) unsigned int*)lds, 16, 0, 0);
}

// ---------------------------------------------------------------------------
// Kernel P: fused preprocessing.
//   ROUND 10 (G11): grid-stride sections, 3264 blocks total (was 18624
//   tiny blocks):
//     [0,2048)     : X fp32 -> bf16, 8 float4 per thread, stride 2048*256
//     [2048,3072)  : xpos tables, 2 entries per thread
//     [3072,3264)  : W transpose+convert -> Wt
// ---------------------------------------------------------------------------
__global__ __launch_bounds__(256) void prep_kernel(
    const float* __restrict__ X, unsigned short* __restrict__ Xb,
    float2* __restrict__ tabQ, float2* __restrict__ tabK,
    const float* __restrict__ WQ, const float* __restrict__ WK,
    const float* __restrict__ WV, unsigned short* __restrict__ Wt)
{
    __shared__ float Ts[64][68];   // used by the transpose section only
    const int bid = blockIdx.x;
    const int t   = threadIdx.x;

    if (bid < 2048) {
        // ---- convert X: 2048 blocks x 256 thr x 8 float4 = 16.7M floats ----
        const int base = bid * 256 + t;          // 0 .. 524287
        #pragma unroll
        for (int it = 0; it < 8; ++it) {
            const int i = (base + it * 524288) * 4;
            const float4 v = *(const float4*)&X[i];
            ushort4 p;
            p.x = f2bf(v.x); p.y = f2bf(v.y); p.z = f2bf(v.z); p.w = f2bf(v.w);
            *(ushort4*)&Xb[i] = p;
        }
    } else if (bid < 3072) {
        // ---- xpos tables: tab[i2][pos], pos-major; 2 entries/thread ----
        const int base = (bid - 2048) * 256 + t;          // 0 .. 262143
        #pragma unroll
        for (int e = 0; e < 2; ++e) {
            const int gid = base + e * 262144;            // 0 .. 524287
            const int i2  = gid >> 12;                    // 0..127
            const int pos = gid & (L_SEQ - 1);
            const float ex  = (float)pos * (1.0f / 512.0f);
            const float sb  = ((float)(2 * i2) + 102.4f) * (1.0f / 358.4f);
            const float scQ = exp2f(log2f(sb) * ex);
            const float scK = 1.0f / scQ;
            const float invf = exp2f(-13.287712379549449f *
                                     ((float)i2 * (1.0f / 128.0f)));
            float s, c;
            sincosf((float)pos * invf, &s, &c);
            tabQ[gid] = make_float2(c * scQ, s * scQ);
            tabK[gid] = make_float2(c * scK, s * scK);
        }
    } else {
        // ---- W transpose: [1024][256] fp32 -> Wt bf16 [768][1024] ----
        const int idx = bid - 3072;           // 0..191
        const int n0 = (idx % 12) * 64;       // 0..704
        const int k0 = (idx / 12) * 64;       // 0..960
        const int seg = n0 >> 8;
        const float* __restrict__ W = (seg == 0) ? WQ : (seg == 1) ? WK : WV;
        const int nl0 = n0 & 255;

        const int r  = t >> 4;          // 0..15
        const int c4 = (t & 15) * 4;
        #pragma unroll
        for (int i = 0; i < 4; ++i) {
            const int kk = r + i * 16;
            const float4 v = *(const float4*)&W[(size_t)(k0 + kk) * DH + nl0 + c4];
            Ts[c4 + 0][kk] = v.x;
            Ts[c4 + 1][kk] = v.y;
            Ts[c4 + 2][kk] = v.z;
            Ts[c4 + 3][kk] = v.w;
        }
        __syncthreads();
        const int rn = t >> 3;          // 0..31
        const int c8 = (t & 7) * 8;
        #pragma unroll
        for (int i = 0; i < 2; ++i) {
            const int rr = rn + i * 32;
            ushort4 p0, p1;
            p0.x = f2bf(Ts[rr][c8 + 0]); p0.y = f2bf(Ts[rr][c8 + 1]);
            p0.z = f2bf(Ts[rr][c8 + 2]); p0.w = f2bf(Ts[rr][c8 + 3]);
            p1.x = f2bf(Ts[rr][c8 + 4]); p1.y = f2bf(Ts[rr][c8 + 5]);
            p1.z = f2bf(Ts[rr][c8 + 6]); p1.w = f2bf(Ts[rr][c8 + 7]);
            unsigned short* dst = &Wt[(size_t)(n0 + rr) * HID + k0 + c8];
            *(ushort4*)dst       = p0;
            *(ushort4*)(dst + 4) = p1;
        }
    }
}

// ---------------------------------------------------------------------------
// Kernel C: QKV projection via bf16 MFMA (unchanged from round 8/9).
//   BK=64, 2-buffer, counted-vmcnt phase-split, chunk-XOR LDS layout.
//   Structure-pinned at ~52 us / 495 TF for this shape (m102 curve) —
//   frozen.
// ---------------------------------------------------------------------------
__global__ __launch_bounds__(256) void gemm_qkv_kernel(
    const unsigned short* __restrict__ Wt,   // [768][1024]
    const unsigned short* __restrict__ Xb,   // [16384][1024]
    const float2* __restrict__ tabQ,         // [128][4096]
    const float2* __restrict__ tabK,         // [128][4096]
    unsigned short* __restrict__ Qo,
    unsigned short* __restrict__ Ko,
    unsigned short* __restrict__ VtG)
{
    __shared__ unsigned short Wa[2][128][64];   // 32 KB
    __shared__ unsigned short Xs[2][128][64];   // 32 KB

    const int dblk = blockIdx.x;
    const int xcd  = dblk & 7;
    const int sq   = dblk >> 3;        // 0..95
    const int by   = xcd * 16 + sq / 6;
    const int bx   = sq % 6;

    const int n0 = bx * 128;   // 0..640
    const int p0 = by * 128;   // 0..16256
    const int t    = threadIdx.x;
    const int w    = t >> 6;
    const int lane = t & 63;
    const int quad = lane >> 4;
    const int l16  = lane & 15;
    const int wn   = (w & 1) * 64;
    const int wp   = (w >> 1) * 64;

    floatx4 acc[4][4];
    #pragma unroll
    for (int i = 0; i < 4; ++i)
        #pragma unroll
        for (int j = 0; j < 4; ++j) acc[i][j] = (floatx4){0.f, 0.f, 0.f, 0.f};

    const int NT = HID / 64;   // 16 K-tiles

    const int g8 = lane >> 3;          // 0..7
    const int pc = lane & 7;           // physical chunk
    const int sc = (pc ^ g8) * 8;      // semantic source col (shorts)
    auto stage = [&](int buf, int kt) {
        const int k0 = kt * 64;
        #pragma unroll
        for (int is = 0; is < 4; ++is) {
            const int gr = w * 8 + is * 32 + g8;   // row in 128-tile
            const unsigned short* ga =
                &Wt[(size_t)(n0 + gr) * HID + k0 + sc];
            const unsigned short* gb =
                &Xb[(size_t)(p0 + gr) * HID + k0 + sc];
            async_copy16(ga, &Wa[buf][is * 32 + w * 8][0]);
            async_copy16(gb, &Xs[buf][is * 32 + w * 8][0]);
        }
    };

    stage(0, 0);
    stage(1, 1);

    const int xr = l16 & 7;   // read-side XOR key

    for (int kt = 0; kt < NT; ++kt) {
        const int buf = kt & 1;
        if (kt + 1 < NT)
            asm volatile("s_waitcnt vmcnt(8)" ::: "memory");
        else
            asm volatile("s_waitcnt vmcnt(0)" ::: "memory");
        __builtin_amdgcn_s_barrier();

        const char* wbp = (const char*)&Wa[buf][0][0];
        const char* xbp = (const char*)&Xs[buf][0][0];
        short8 af[2][4], bfv[2][4];
        #pragma unroll
        for (int kk = 0; kk < 2; ++kk) {
            const int pk = (((kk << 2) | quad) ^ xr) << 4;   // chunk byte
            #pragma unroll
            for (int nt = 0; nt < 4; ++nt) {
                af[kk][nt]  = *(const short8*)(wbp + (wn + nt * 16 + l16) * 128 + pk);
                bfv[kk][nt] = *(const short8*)(xbp + (wp + nt * 16 + l16) * 128 + pk);
            }
        }
        asm volatile("s_waitcnt lgkmcnt(0)" ::: "memory");
        __builtin_amdgcn_s_barrier();

        if (kt + 2 < NT) stage(buf, kt + 2);

        #pragma unroll
        for (int kk = 0; kk < 2; ++kk)
            #pragma unroll
            for (int nt = 0; nt < 4; ++nt)
                #pragma unroll
                for (int pt = 0; pt < 4; ++pt)
                    acc[nt][pt] = __builtin_amdgcn_mfma_f32_16x16x32_bf16(
                        af[kk][nt], bfv[kk][pt], acc[nt][pt], 0, 0, 0);
    }

    // ---- epilogue ----
    const int seg = n0 >> 8;     // 0=Q 1=K 2=V
    const float2* __restrict__ tab = (seg == 1) ? tabK : tabQ;
    #pragma unroll
    for (int nt = 0; nt < 4; ++nt) {
        const int nfeat = n0 + wn + nt * 16 + quad * 4;  // feat of reg g=0
        const int d0 = nfeat & 255;                      // segment-local
        #pragma unroll
        for (int pt = 0; pt < 4; ++pt) {
            const int pg  = p0 + wp + pt * 16 + l16;     // global row
            const int b   = pg >> 12;
            const int pos = pg & (L_SEQ - 1);
            if (seg == 2) {
                #pragma unroll
                for (int g = 0; g < 4; ++g)
                    VtG[(((size_t)(b * 256 + d0 + g)) << 12) + pos] =
                        f2bf(acc[nt][pt][g]);
            } else {
                float res[4];
                #pragma unroll
                for (int h = 0; h < 4; h += 2) {
                    const int i2 = (d0 + h) >> 1;
                    const float2 tc = tab[(i2 << 12) + pos];
                    const float cs = tc.x, ss = tc.y;
                    const float xe = acc[nt][pt][h], xo = acc[nt][pt][h + 1];
                    res[h]     = xe * cs - xo * ss;
                    res[h + 1] = xo * cs + xe * ss;
                }
                ushort4 pk;
                pk.x = f2bf(res[0]); pk.y = f2bf(res[1]);
                pk.z = f2bf(res[2]); pk.w = f2bf(res[3]);
                unsigned short* orow =
                    ((seg == 0) ? Qo : Ko) + (size_t)pg * DH + d0;
                *(ushort4*)orow = pk;
            }
        }
    }
}

// ---------------------------------------------------------------------------
// Kernel D: windowed retention via bf16 MFMA.
//   ROUND 10: z4 feature-quarter split (64 V-feats/block, grid 1024 =
//   4 blocks/CU, LDS 40 KB). QK^T duplicated 4x (cheap: ~2.3 us chip-wide
//   MFMA issue) for 2x TLP in a latency-bound loop. V staging: 1 async
//   op/thread. 2-phase pipeline + XOR swizzles + setprio kept from R9.
// ---------------------------------------------------------------------------
__global__ __launch_bounds__(256) void retention_kernel(
    const unsigned short* __restrict__ Q,
    const unsigned short* __restrict__ K,
    const unsigned short* __restrict__ VtG,
    float* __restrict__ O)
{
    __shared__ unsigned short Ks[2][32][256];   // 32 KB
    __shared__ unsigned short Vt[2][64][32];    // 8 KB

    const int dblk = blockIdx.x;                // 0..1023
    const int xcd  = dblk & 7;
    const int sq   = dblk >> 3;           // 0..127
    const int qt   = xcd * 8 + (sq & 7);  // 0..63
    const int b    = (sq >> 3) & 3;
    const int z    = sq >> 5;             // feature quarter 0..3

    const int t  = threadIdx.x;
    const int q0 = qt * 64;

    const int w    = t >> 6;
    const int lane = t & 63;
    const int quad = lane >> 4;
    const int l16  = lane & 15;
    const int w16  = w * 16;

    const size_t rbase = (size_t)b * L_SEQ * DH;
    const size_t vbase = ((size_t)b * DH) << 12;

    int kst = q0 - 512; if (kst < 0) kst = 0;
    const int nsteps = ((q0 + 64) - kst) >> 5;

    // ---- staging constants (source pre-swizzle) ----
    // K: issue i covers LDS rows i*8 + w*2 + (lane>>5), chunk p = lane&31;
    //    semantic col = (p ^ (row&7))*8 shorts.
    const int krow = w * 2 + (lane >> 5);               // + i*8
    const int kscol = ((lane & 31) ^ (krow & 7)) * 8;
    // V: one issue covers LDS rows w*16 + (lane>>2), chunk p = lane&3;
    //    semantic col = (p ^ ((row>>1)&3))*8 = (p ^ ((lane>>3)&3))*8.
    const int vrow = w * 16 + (lane >> 2);
    const int vscol = ((lane & 3) ^ ((lane >> 3) & 3)) * 8;

    auto stage = [&](int buf, int k0) {
        const unsigned short* ksrc = K + rbase + (size_t)k0 * DH;
        #pragma unroll
        for (int i = 0; i < 4; ++i)
            async_copy16(&ksrc[(size_t)(i * 8 + krow) * DH + kscol],
                         &Ks[buf][i * 8 + w * 2][0]);
        async_copy16(&VtG[vbase + ((size_t)(z * 64 + vrow) << 12) + k0 + vscol],
                     &Vt[buf][w * 16][0]);
    };

    // Q fragments in registers: B-frag for swapped mfma.
    short8 qf[8];
    {
        const unsigned short* qsrc = Q + rbase + (size_t)(q0 + w16 + l16) * DH;
        #pragma unroll
        for (int dd = 0; dd < 8; ++dd)
            qf[dd] = *(const short8*)&qsrc[dd * 32 + quad * 8];
    }

    // running decay state per (nt,g): d = qpos - kpos at current k0
    int   dint[8];
    float dec[8];
    #pragma unroll
    for (int nt = 0; nt < 2; ++nt)
        #pragma unroll
        for (int g = 0; g < 4; ++g) {
            const int idx = nt * 4 + g;
            dint[idx] = (q0 + w16 + l16) - (kst + nt * 16 + quad * 4 + g);
            dec[idx]  = exp2f((float)dint[idx] * LOG2_GAMMA);
        }

    floatx4 o[4];
    #pragma unroll
    for (int f = 0; f < 4; ++f) o[f] = (floatx4){0.f, 0.f, 0.f, 0.f};

    // bpermute source-lane byte indices (constant per lane)
    const int s0   = (quad & 1) * 2;
    const int idxA = (s0 * 16 + l16) * 4;
    const int idxB = idxA + 64;
    const bool lo  = (quad < 2);   // target k-subtile nt = quad>>1

    // read-side swizzle keys
    const int xk7 = l16 & 7;                          // K chunks
    const int pvx = (quad ^ ((l16 >> 1) & 3)) << 4;   // V chunk byte

    // ---- prologue ----
    stage(0, kst);
    asm volatile("s_waitcnt vmcnt(0)" ::: "memory");
    __builtin_amdgcn_s_barrier();

    for (int it = 0; it < nsteps; ++it) {
        const int cur = it & 1;
        const int k0  = kst + it * 32;
        if (it + 1 < nsteps) stage(cur ^ 1, k0 + 32);

        const char* kb = (const char*)&Ks[cur][0][0];
        const char* vb = (const char*)&Vt[cur][0][0];

        // ---- swapped QK^T: A = K rows (LDS), B = Q regs; 4 chains
        floatx4 sA0 = (floatx4){0.f, 0.f, 0.f, 0.f};
        floatx4 sA1 = (floatx4){0.f, 0.f, 0.f, 0.f};
        floatx4 sB0 = (floatx4){0.f, 0.f, 0.f, 0.f};
        floatx4 sB1 = (floatx4){0.f, 0.f, 0.f, 0.f};
        __builtin_amdgcn_s_setprio(1);
        #pragma unroll
        for (int dd = 0; dd < 4; ++dd) {
            const int c0 = ((dd * 4 + quad) ^ xk7) << 4;
            const int c1 = (((dd + 4) * 4 + quad) ^ xk7) << 4;
            const short8 k0f = *(const short8*)(kb + l16 * 512 + c0);
            const short8 k1f = *(const short8*)(kb + (16 + l16) * 512 + c0);
            const short8 k0g = *(const short8*)(kb + l16 * 512 + c1);
            const short8 k1g = *(const short8*)(kb + (16 + l16) * 512 + c1);
            sA0 = __builtin_amdgcn_mfma_f32_16x16x32_bf16(k0f, qf[dd], sA0, 0, 0, 0);
            sA1 = __builtin_amdgcn_mfma_f32_16x16x32_bf16(k1f, qf[dd], sA1, 0, 0, 0);
            sB0 = __builtin_amdgcn_mfma_f32_16x16x32_bf16(k0g, qf[dd + 4], sB0, 0, 0, 0);
            sB1 = __builtin_amdgcn_mfma_f32_16x16x32_bf16(k1g, qf[dd + 4], sB1, 0, 0, 0);
        }
        __builtin_amdgcn_s_setprio(0);
        const floatx4 sv0 = sA0 + sB0;   // nt=0: kpos = k0 + quad*4+g
        const floatx4 sv1 = sA1 + sB1;   // nt=1: kpos = k0+16 + quad*4+g

        // ---- decay + pack to bf16 pairs (lane-local)
        unsigned int pk01[2], pk23[2];
        #pragma unroll
        for (int nt = 0; nt < 2; ++nt) {
            const floatx4 sv = nt ? sv1 : sv0;
            float pv[4];
            #pragma unroll
            for (int g = 0; g < 4; ++g) {
                const int idx = nt * 4 + g;
                pv[g] = (dint[idx] >= 0) ? sv[g] * dec[idx] : 0.0f;
            }
            pk01[nt] = ((unsigned int)f2bf(pv[1]) << 16) | (unsigned int)f2bf(pv[0]);
            pk23[nt] = ((unsigned int)f2bf(pv[3]) << 16) | (unsigned int)f2bf(pv[2]);
        }
        #pragma unroll
        for (int i = 0; i < 8; ++i) { dint[i] -= 32; dec[i] *= INV_GAMMA32; }

        // ---- redistribute P to PV A-frag layout: 8 bpermute + 4 selects
        const int a01_0 = __builtin_amdgcn_ds_bpermute(idxA, (int)pk01[0]);
        const int a01_1 = __builtin_amdgcn_ds_bpermute(idxA, (int)pk01[1]);
        const int a23_0 = __builtin_amdgcn_ds_bpermute(idxA, (int)pk23[0]);
        const int a23_1 = __builtin_amdgcn_ds_bpermute(idxA, (int)pk23[1]);
        const int b01_0 = __builtin_amdgcn_ds_bpermute(idxB, (int)pk01[0]);
        const int b01_1 = __builtin_amdgcn_ds_bpermute(idxB, (int)pk01[1]);
        const int b23_0 = __builtin_amdgcn_ds_bpermute(idxB, (int)pk23[0]);
        const int b23_1 = __builtin_amdgcn_ds_bpermute(idxB, (int)pk23[1]);
        union { int u[4]; short8 s8; } af;
        af.u[0] = lo ? a01_0 : a01_1;
        af.u[1] = lo ? a23_0 : a23_1;
        af.u[2] = lo ? b01_0 : b01_1;
        af.u[3] = lo ? b23_0 : b23_1;

        // ---- PV: o[f] += P @ V^T  (A from regs, B from swizzled Vt LDS)
        __builtin_amdgcn_s_setprio(1);
        #pragma unroll
        for (int f = 0; f < 4; ++f) {
            const short8 bfr =
                *(const short8*)(vb + (f * 16 + l16) * 64 + pvx);
            o[f] = __builtin_amdgcn_mfma_f32_16x16x32_bf16(af.s8, bfr, o[f], 0, 0, 0);
        }
        __builtin_amdgcn_s_setprio(0);

        // next tile staged; all reads of cur consumed
        asm volatile("s_waitcnt vmcnt(0)" ::: "memory");
        __builtin_amdgcn_s_barrier();
    }

    // direct store: this block owns features z*64 .. z*64+63 exclusively
    #pragma unroll
    for (int f = 0; f < 4; ++f) {
        #pragma unroll
        for (int g = 0; g < 4; ++g) {
            const int qpos = q0 + w16 + quad * 4 + g;
            O[rbase + (size_t)qpos * DH + z * 64 + f * 16 + l16] = o[f][g];
        }
    }
}

// ---------------------------------------------------------------------------
extern "C" void kernel_launch(void* const* d_in, const int* in_sizes, int n_in,
                              void* d_out, int out_size, void* d_ws, size_t ws_size,
                              hipStream_t stream)
{
    const float* X  = (const float*)d_in[0];
    const float* WQ = (const float*)d_in[1];
    const float* WK = (const float*)d_in[2];
    const float* WV = (const float*)d_in[3];
    float* out = (float*)d_out;

    const size_t per = (size_t)BATCH_N * L_SEQ * DH;   // 4,194,304
    unsigned short* Qw  = (unsigned short*)d_ws;
    unsigned short* Kw  = Qw + per;
    unsigned short* Vtw = Kw + per;
    unsigned short* Xbw = Vtw + per;                   // 16,777,216 elems
    unsigned short* Wtw = Xbw + (size_t)16384 * HID;   // 786,432 elems
    float2* tabQ = (float2*)(Wtw + 786432);            // 4 MB (8B-aligned)
    float2* tabK = tabQ + (size_t)128 * L_SEQ;         // 4 MB
    // total workspace: ~68.3 MB

    prep_kernel<<<3264, 256, 0, stream>>>(X, Xbw, tabQ, tabK,
                                          WQ, WK, WV, Wtw);

    gemm_qkv_kernel<<<768, 256, 0, stream>>>(Wtw, Xbw, tabQ, tabK, Qw, Kw, Vtw);

    retention_kernel<<<1024, 256, 0, stream>>>(Qw, Kw, Vtw, out);
}

// Round 11
// 196.860 us; speedup vs baseline: 1.0116x; 1.0116x over previous
//
#include <hip/hip_runtime.h>
#include <hip/hip_bf16.h>
#include <cstdint>
#include <cstddef>

#define L_SEQ 4096
#define BATCH_N 4
#define HID 1024
#define DH 256
// log2(0.96875)
#define LOG2_GAMMA (-0.045803689613124953f)
// 0.96875^-32
#define INV_GAMMA32 (2.7620582f)

typedef __attribute__((ext_vector_type(8))) short short8;
typedef __attribute__((ext_vector_type(4))) float floatx4;

__device__ __forceinline__ unsigned short f2bf(float f) {
    union { float f; unsigned int u; } v; v.f = f;
    unsigned int r = (v.u + 0x7FFFu + ((v.u >> 16) & 1u)) >> 16;  // RNE
    return (unsigned short)r;
}

__device__ __forceinline__ void async_copy16(const unsigned short* gsrc,
                                             unsigned short* lds) {
    __builtin_amdgcn_global_load_lds(
        (const __attribute__((address_space(1))) unsigned int*)gsrc,
        (__attribute__((address_space(3))) unsigned int*)lds, 16, 0, 0);
}

// pack two f32 -> one u32 of 2 bf16 (RNE, bit-identical to f2bf on normals)
__device__ __forceinline__ unsigned int cvt_pk_bf16(float lo, float hi) {
    unsigned int r;
    asm volatile("v_cvt_pk_bf16_f32 %0, %1, %2" : "=v"(r) : "v"(lo), "v"(hi));
    return r;
}

// ---------------------------------------------------------------------------
// Kernel P: preprocessing. ROUND 11: convert_x section REMOVED (fused into
// gemm). Sections:
//   [0,1024)     : xpos tables, 2 entries per thread
//   [1024,1216)  : W transpose+convert -> Wt
// ---------------------------------------------------------------------------
__global__ __launch_bounds__(256) void prep_kernel(
    float2* __restrict__ tabQ, float2* __restrict__ tabK,
    const float* __restrict__ WQ, const float* __restrict__ WK,
    const float* __restrict__ WV, unsigned short* __restrict__ Wt)
{
    __shared__ float Ts[64][68];   // used by the transpose section only
    const int bid = blockIdx.x;
    const int t   = threadIdx.x;

    if (bid < 1024) {
        // ---- xpos tables: tab[i2][pos], pos-major; 2 entries/thread ----
        const int base = bid * 256 + t;                   // 0 .. 262143
        #pragma unroll
        for (int e = 0; e < 2; ++e) {
            const int gid = base + e * 262144;            // 0 .. 524287
            const int i2  = gid >> 12;                    // 0..127
            const int pos = gid & (L_SEQ - 1);
            const float ex  = (float)pos * (1.0f / 512.0f);
            const float sb  = ((float)(2 * i2) + 102.4f) * (1.0f / 358.4f);
            const float scQ = exp2f(log2f(sb) * ex);
            const float scK = 1.0f / scQ;
            const float invf = exp2f(-13.287712379549449f *
                                     ((float)i2 * (1.0f / 128.0f)));
            float s, c;
            sincosf((float)pos * invf, &s, &c);
            tabQ[gid] = make_float2(c * scQ, s * scQ);
            tabK[gid] = make_float2(c * scK, s * scK);
        }
    } else {
        // ---- W transpose: [1024][256] fp32 -> Wt bf16 [768][1024] ----
        const int idx = bid - 1024;           // 0..191
        const int n0 = (idx % 12) * 64;       // 0..704
        const int k0 = (idx / 12) * 64;       // 0..960
        const int seg = n0 >> 8;
        const float* __restrict__ W = (seg == 0) ? WQ : (seg == 1) ? WK : WV;
        const int nl0 = n0 & 255;

        const int r  = t >> 4;          // 0..15
        const int c4 = (t & 15) * 4;
        #pragma unroll
        for (int i = 0; i < 4; ++i) {
            const int kk = r + i * 16;
            const float4 v = *(const float4*)&W[(size_t)(k0 + kk) * DH + nl0 + c4];
            Ts[c4 + 0][kk] = v.x;
            Ts[c4 + 1][kk] = v.y;
            Ts[c4 + 2][kk] = v.z;
            Ts[c4 + 3][kk] = v.w;
        }
        __syncthreads();
        const int rn = t >> 3;          // 0..31
        const int c8 = (t & 7) * 8;
        #pragma unroll
        for (int i = 0; i < 2; ++i) {
            const int rr = rn + i * 32;
            ushort4 p0, p1;
            p0.x = f2bf(Ts[rr][c8 + 0]); p0.y = f2bf(Ts[rr][c8 + 1]);
            p0.z = f2bf(Ts[rr][c8 + 2]); p0.w = f2bf(Ts[rr][c8 + 3]);
            p1.x = f2bf(Ts[rr][c8 + 4]); p1.y = f2bf(Ts[rr][c8 + 5]);
            p1.z = f2bf(Ts[rr][c8 + 6]); p1.w = f2bf(Ts[rr][c8 + 7]);
            unsigned short* dst = &Wt[(size_t)(n0 + rr) * HID + k0 + c8];
            *(ushort4*)dst       = p0;
            *(ushort4*)(dst + 4) = p1;
        }
    }
}

// ---------------------------------------------------------------------------
// Kernel C: QKV projection via bf16 MFMA.
//   ROUND 11: X read directly as fp32 (convert fused). Per K-tile, each
//   thread: 8 global_load_dwordx4 (X fp32, issued ONE PHASE AHEAD into regs)
//   -> v_cvt_pk_bf16_f32 x16 -> 4 ds_write_b128 into the SAME XOR-chunk
//   Xs layout as before. Wa keeps async global_load_lds. ds_writes drain
//   via top-of-phase lgkmcnt(0) before barrier A (cross-wave visibility);
//   top wait = vmcnt(4*[kt+1<NT] + 8*[kt+2<NT]). Frag reads + epilogue
//   unchanged. Kills prep's 128 MB convert pass + the 32 MB Xb buffer.
// ---------------------------------------------------------------------------
__global__ __launch_bounds__(256) void gemm_qkv_kernel(
    const float* __restrict__ X,             // [16384][1024] fp32
    const unsigned short* __restrict__ Wt,   // [768][1024]
    const float2* __restrict__ tabQ,         // [128][4096]
    const float2* __restrict__ tabK,         // [128][4096]
    unsigned short* __restrict__ Qo,
    unsigned short* __restrict__ Ko,
    unsigned short* __restrict__ VtG)
{
    __shared__ unsigned short Wa[2][128][64];   // 32 KB
    __shared__ unsigned short Xs[2][128][64];   // 32 KB

    const int dblk = blockIdx.x;
    const int xcd  = dblk & 7;
    const int sq   = dblk >> 3;        // 0..95
    const int by   = xcd * 16 + sq / 6;
    const int bx   = sq % 6;

    const int n0 = bx * 128;   // 0..640
    const int p0 = by * 128;   // 0..16256
    const int t    = threadIdx.x;
    const int w    = t >> 6;
    const int lane = t & 63;
    const int quad = lane >> 4;
    const int l16  = lane & 15;
    const int wn   = (w & 1) * 64;
    const int wp   = (w >> 1) * 64;

    floatx4 acc[4][4];
    #pragma unroll
    for (int i = 0; i < 4; ++i)
        #pragma unroll
        for (int j = 0; j < 4; ++j) acc[i][j] = (floatx4){0.f, 0.f, 0.f, 0.f};

    const int NT = HID / 64;   // 16 K-tiles

    const int g8 = lane >> 3;          // 0..7 (row within 8-row group)
    const int pc = lane & 7;           // physical chunk
    const int sc = (pc ^ g8) * 8;      // semantic source col (elements)

    // Wa staging: async, 2 tiles ahead (unchanged)
    auto stageW = [&](int buf, int kt) {
        const int k0 = kt * 64;
        #pragma unroll
        for (int is = 0; is < 4; ++is) {
            const int gr = w * 8 + is * 32 + g8;   // row in 128-tile
            async_copy16(&Wt[(size_t)(n0 + gr) * HID + k0 + sc],
                         &Wa[buf][is * 32 + w * 8][0]);
        }
    };

    // X staging: fp32 -> regs (one phase ahead)
    float4 xr[8];
    auto loadX = [&](int kt) {
        const int k0 = kt * 64;
        #pragma unroll
        for (int is = 0; is < 4; ++is) {
            const int gr = w * 8 + is * 32 + g8;
            const float* xp = &X[(size_t)(p0 + gr) * HID + k0 + sc];
            xr[is * 2]     = *(const float4*)xp;
            xr[is * 2 + 1] = *(const float4*)(xp + 4);
        }
    };
    // convert + write to the linear dest async_copy16 would have used
    auto writeX = [&](int buf) {
        #pragma unroll
        for (int is = 0; is < 4; ++is) {
            uint4 pk;
            pk.x = cvt_pk_bf16(xr[is * 2].x,     xr[is * 2].y);
            pk.y = cvt_pk_bf16(xr[is * 2].z,     xr[is * 2].w);
            pk.z = cvt_pk_bf16(xr[is * 2 + 1].x, xr[is * 2 + 1].y);
            pk.w = cvt_pk_bf16(xr[is * 2 + 1].z, xr[is * 2 + 1].w);
            unsigned short* dst = &Xs[buf][is * 32 + w * 8][0] + (size_t)lane * 8;
            *(uint4*)dst = pk;
        }
    };

    // ---- prologue: tiles 0 and 1 fully staged; X(2) loads in flight ----
    loadX(0);
    stageW(0, 0);
    writeX(0);           // compiler-inserted vmcnt drains xr (prologue only)
    loadX(1);
    stageW(1, 1);
    writeX(1);
    if (NT > 2) loadX(2);

    const int xr7 = l16 & 7;   // read-side XOR key

    for (int kt = 0; kt < NT; ++kt) {
        const int buf = kt & 1;
        // Wa(kt) + X-writes(kt) complete; keep phase kt-1's issues in
        // flight: Wa(kt+1) [4] + X-loads(kt+2) [8]
        if (kt + 2 < NT)
            asm volatile("s_waitcnt vmcnt(12) lgkmcnt(0)" ::: "memory");
        else if (kt + 1 < NT)
            asm volatile("s_waitcnt vmcnt(4) lgkmcnt(0)" ::: "memory");
        else
            asm volatile("s_waitcnt vmcnt(0) lgkmcnt(0)" ::: "memory");
        __builtin_amdgcn_s_barrier();

        // read ALL fragments for this 64-wide K-tile into registers
        const char* wbp = (const char*)&Wa[buf][0][0];
        const char* xbp = (const char*)&Xs[buf][0][0];
        short8 af[2][4], bfv[2][4];
        #pragma unroll
        for (int kk = 0; kk < 2; ++kk) {
            const int pk = (((kk << 2) | quad) ^ xr7) << 4;   // chunk byte
            #pragma unroll
            for (int nt = 0; nt < 4; ++nt) {
                af[kk][nt]  = *(const short8*)(wbp + (wn + nt * 16 + l16) * 128 + pk);
                bfv[kk][nt] = *(const short8*)(xbp + (wp + nt * 16 + l16) * 128 + pk);
            }
        }
        asm volatile("s_waitcnt lgkmcnt(0)" ::: "memory");
        __builtin_amdgcn_s_barrier();

        // refill this buffer for tile kt+2 while MFMAs run
        if (kt + 2 < NT) {
            writeX(buf);            // xr holds X(kt+2)
            stageW(buf, kt + 2);
            if (kt + 3 < NT) loadX(kt + 3);
        }

        #pragma unroll
        for (int kk = 0; kk < 2; ++kk)
            #pragma unroll
            for (int nt = 0; nt < 4; ++nt)
                #pragma unroll
                for (int pt = 0; pt < 4; ++pt)
                    acc[nt][pt] = __builtin_amdgcn_mfma_f32_16x16x32_bf16(
                        af[kk][nt], bfv[kk][pt], acc[nt][pt], 0, 0, 0);
    }

    // ---- epilogue ----
    const int seg = n0 >> 8;     // 0=Q 1=K 2=V
    const float2* __restrict__ tab = (seg == 1) ? tabK : tabQ;
    #pragma unroll
    for (int nt = 0; nt < 4; ++nt) {
        const int nfeat = n0 + wn + nt * 16 + quad * 4;  // feat of reg g=0
        const int d0 = nfeat & 255;                      // segment-local
        #pragma unroll
        for (int pt = 0; pt < 4; ++pt) {
            const int pg  = p0 + wp + pt * 16 + l16;     // global row
            const int b   = pg >> 12;
            const int pos = pg & (L_SEQ - 1);
            if (seg == 2) {
                #pragma unroll
                for (int g = 0; g < 4; ++g)
                    VtG[(((size_t)(b * 256 + d0 + g)) << 12) + pos] =
                        f2bf(acc[nt][pt][g]);
            } else {
                float res[4];
                #pragma unroll
                for (int h = 0; h < 4; h += 2) {
                    const int i2 = (d0 + h) >> 1;
                    const float2 tc = tab[(i2 << 12) + pos];
                    const float cs = tc.x, ss = tc.y;
                    const float xe = acc[nt][pt][h], xo = acc[nt][pt][h + 1];
                    res[h]     = xe * cs - xo * ss;
                    res[h + 1] = xo * cs + xe * ss;
                }
                ushort4 pk;
                pk.x = f2bf(res[0]); pk.y = f2bf(res[1]);
                pk.z = f2bf(res[2]); pk.w = f2bf(res[3]);
                unsigned short* orow =
                    ((seg == 0) ? Qo : Ko) + (size_t)pg * DH + d0;
                *(ushort4*)orow = pk;
            }
        }
    }
}

// ---------------------------------------------------------------------------
// Kernel D: windowed retention via bf16 MFMA (unchanged from round 10:
// z4 feature-quarter split, 1024 blocks = 4 blocks/CU, 2-phase pipeline,
// XOR swizzles, setprio, direct stores).
// ---------------------------------------------------------------------------
__global__ __launch_bounds__(256) void retention_kernel(
    const unsigned short* __restrict__ Q,
    const unsigned short* __restrict__ K,
    const unsigned short* __restrict__ VtG,
    float* __restrict__ O)
{
    __shared__ unsigned short Ks[2][32][256];   // 32 KB
    __shared__ unsigned short Vt[2][64][32];    // 8 KB

    const int dblk = blockIdx.x;                // 0..1023
    const int xcd  = dblk & 7;
    const int sq   = dblk >> 3;           // 0..127
    const int qt   = xcd * 8 + (sq & 7);  // 0..63
    const int b    = (sq >> 3) & 3;
    const int z    = sq >> 5;             // feature quarter 0..3

    const int t  = threadIdx.x;
    const int q0 = qt * 64;

    const int w    = t >> 6;
    const int lane = t & 63;
    const int quad = lane >> 4;
    const int l16  = lane & 15;
    const int w16  = w * 16;

    const size_t rbase = (size_t)b * L_SEQ * DH;
    const size_t vbase = ((size_t)b * DH) << 12;

    int kst = q0 - 512; if (kst < 0) kst = 0;
    const int nsteps = ((q0 + 64) - kst) >> 5;

    const int krow = w * 2 + (lane >> 5);               // + i*8
    const int kscol = ((lane & 31) ^ (krow & 7)) * 8;
    const int vrow = w * 16 + (lane >> 2);
    const int vscol = ((lane & 3) ^ ((lane >> 3) & 3)) * 8;

    auto stage = [&](int buf, int k0) {
        const unsigned short* ksrc = K + rbase + (size_t)k0 * DH;
        #pragma unroll
        for (int i = 0; i < 4; ++i)
            async_copy16(&ksrc[(size_t)(i * 8 + krow) * DH + kscol],
                         &Ks[buf][i * 8 + w * 2][0]);
        async_copy16(&VtG[vbase + ((size_t)(z * 64 + vrow) << 12) + k0 + vscol],
                     &Vt[buf][w * 16][0]);
    };

    short8 qf[8];
    {
        const unsigned short* qsrc = Q + rbase + (size_t)(q0 + w16 + l16) * DH;
        #pragma unroll
        for (int dd = 0; dd < 8; ++dd)
            qf[dd] = *(const short8*)&qsrc[dd * 32 + quad * 8];
    }

    int   dint[8];
    float dec[8];
    #pragma unroll
    for (int nt = 0; nt < 2; ++nt)
        #pragma unroll
        for (int g = 0; g < 4; ++g) {
            const int idx = nt * 4 + g;
            dint[idx] = (q0 + w16 + l16) - (kst + nt * 16 + quad * 4 + g);
            dec[idx]  = exp2f((float)dint[idx] * LOG2_GAMMA);
        }

    floatx4 o[4];
    #pragma unroll
    for (int f = 0; f < 4; ++f) o[f] = (floatx4){0.f, 0.f, 0.f, 0.f};

    const int s0   = (quad & 1) * 2;
    const int idxA = (s0 * 16 + l16) * 4;
    const int idxB = idxA + 64;
    const bool lo  = (quad < 2);

    const int xk7 = l16 & 7;
    const int pvx = (quad ^ ((l16 >> 1) & 3)) << 4;

    stage(0, kst);
    asm volatile("s_waitcnt vmcnt(0)" ::: "memory");
    __builtin_amdgcn_s_barrier();

    for (int it = 0; it < nsteps; ++it) {
        const int cur = it & 1;
        const int k0  = kst + it * 32;
        if (it + 1 < nsteps) stage(cur ^ 1, k0 + 32);

        const char* kb = (const char*)&Ks[cur][0][0];
        const char* vb = (const char*)&Vt[cur][0][0];

        floatx4 sA0 = (floatx4){0.f, 0.f, 0.f, 0.f};
        floatx4 sA1 = (floatx4){0.f, 0.f, 0.f, 0.f};
        floatx4 sB0 = (floatx4){0.f, 0.f, 0.f, 0.f};
        floatx4 sB1 = (floatx4){0.f, 0.f, 0.f, 0.f};
        __builtin_amdgcn_s_setprio(1);
        #pragma unroll
        for (int dd = 0; dd < 4; ++dd) {
            const int c0 = ((dd * 4 + quad) ^ xk7) << 4;
            const int c1 = (((dd + 4) * 4 + quad) ^ xk7) << 4;
            const short8 k0f = *(const short8*)(kb + l16 * 512 + c0);
            const short8 k1f = *(const short8*)(kb + (16 + l16) * 512 + c0);
            const short8 k0g = *(const short8*)(kb + l16 * 512 + c1);
            const short8 k1g = *(const short8*)(kb + (16 + l16) * 512 + c1);
            sA0 = __builtin_amdgcn_mfma_f32_16x16x32_bf16(k0f, qf[dd], sA0, 0, 0, 0);
            sA1 = __builtin_amdgcn_mfma_f32_16x16x32_bf16(k1f, qf[dd], sA1, 0, 0, 0);
            sB0 = __builtin_amdgcn_mfma_f32_16x16x32_bf16(k0g, qf[dd + 4], sB0, 0, 0, 0);
            sB1 = __builtin_amdgcn_mfma_f32_16x16x32_bf16(k1g, qf[dd + 4], sB1, 0, 0, 0);
        }
        __builtin_amdgcn_s_setprio(0);
        const floatx4 sv0 = sA0 + sB0;
        const floatx4 sv1 = sA1 + sB1;

        unsigned int pk01[2], pk23[2];
        #pragma unroll
        for (int nt = 0; nt < 2; ++nt) {
            const floatx4 sv = nt ? sv1 : sv0;
            float pv[4];
            #pragma unroll
            for (int g = 0; g < 4; ++g) {
                const int idx = nt * 4 + g;
                pv[g] = (dint[idx] >= 0) ? sv[g] * dec[idx] : 0.0f;
            }
            pk01[nt] = ((unsigned int)f2bf(pv[1]) << 16) | (unsigned int)f2bf(pv[0]);
            pk23[nt] = ((unsigned int)f2bf(pv[3]) << 16) | (unsigned int)f2bf(pv[2]);
        }
        #pragma unroll
        for (int i = 0; i < 8; ++i) { dint[i] -= 32; dec[i] *= INV_GAMMA32; }

        const int a01_0 = __builtin_amdgcn_ds_bpermute(idxA, (int)pk01[0]);
        const int a01_1 = __builtin_amdgcn_ds_bpermute(idxA, (int)pk01[1]);
        const int a23_0 = __builtin_amdgcn_ds_bpermute(idxA, (int)pk23[0]);
        const int a23_1 = __builtin_amdgcn_ds_bpermute(idxA, (int)pk23[1]);
        const int b01_0 = __builtin_amdgcn_ds_bpermute(idxB, (int)pk01[0]);
        const int b01_1 = __builtin_amdgcn_ds_bpermute(idxB, (int)pk01[1]);
        const int b23_0 = __builtin_amdgcn_ds_bpermute(idxB, (int)pk23[0]);
        const int b23_1 = __builtin_amdgcn_ds_bpermute(idxB, (int)pk23[1]);
        union { int u[4]; short8 s8; } af;
        af.u[0] = lo ? a01_0 : a01_1;
        af.u[1] = lo ? a23_0 : a23_1;
        af.u[2] = lo ? b01_0 : b01_1;
        af.u[3] = lo ? b23_0 : b23_1;

        __builtin_amdgcn_s_setprio(1);
        #pragma unroll
        for (int f = 0; f < 4; ++f) {
            const short8 bfr =
                *(const short8*)(vb + (f * 16 + l16) * 64 + pvx);
            o[f] = __builtin_amdgcn_mfma_f32_16x16x32_bf16(af.s8, bfr, o[f], 0, 0, 0);
        }
        __builtin_amdgcn_s_setprio(0);

        asm volatile("s_waitcnt vmcnt(0)" ::: "memory");
        __builtin_amdgcn_s_barrier();
    }

    #pragma unroll
    for (int f = 0; f < 4; ++f) {
        #pragma unroll
        for (int g = 0; g < 4; ++g) {
            const int qpos = q0 + w16 + quad * 4 + g;
            O[rbase + (size_t)qpos * DH + z * 64 + f * 16 + l16] = o[f][g];
        }
    }
}

// ---------------------------------------------------------------------------
extern "C" void kernel_launch(void* const* d_in, const int* in_sizes, int n_in,
                              void* d_out, int out_size, void* d_ws, size_t ws_size,
                              hipStream_t stream)
{
    const float* X  = (const float*)d_in[0];
    const float* WQ = (const float*)d_in[1];
    const float* WK = (const float*)d_in[2];
    const float* WV = (const float*)d_in[3];
    float* out = (float*)d_out;

    const size_t per = (size_t)BATCH_N * L_SEQ * DH;   // 4,194,304
    unsigned short* Qw  = (unsigned short*)d_ws;
    unsigned short* Kw  = Qw + per;
    unsigned short* Vtw = Kw + per;
    unsigned short* Wtw = Vtw + per;                   // 786,432 elems
    float2* tabQ = (float2*)(Wtw + 786432);            // 4 MB (8B-aligned)
    float2* tabK = tabQ + (size_t)128 * L_SEQ;         // 4 MB
    // total workspace: ~33.5 MB (Xb eliminated)

    prep_kernel<<<1216, 256, 0, stream>>>(tabQ, tabK, WQ, WK, WV, Wtw);

    gemm_qkv_kernel<<<768, 256, 0, stream>>>(X, Wtw, tabQ, tabK, Qw, Kw, Vtw);

    retention_kernel<<<1024, 256, 0, stream>>>(Qw, Kw, Vtw, out);
}